// Round 8
// baseline (194.849 us; speedup 1.0000x reference)
//
#include <hip/hip_runtime.h>

#define TT 256
#define CC 256
#define LLAB 64
#define EPSF 1e-7f
#define CH 32            // timesteps per chunk
#define NSLOT 4          // LDS ring slots: {reading k, ready k+1, in-flight k+2} + slack
#define LN2F 0.69314718055994531f

// am1[l] = x[l-1]; lane 0 -> 0.0f (prob-domain identity) via `old` operand.
__device__ __forceinline__ float wave_shr1_zero(float x) {
    int r = __builtin_amdgcn_update_dpp(0, __float_as_int(x), 0x138, 0xF, 0xF, false);
    return __int_as_float(r);
}

// Full 64-lane max (values >= 0), wave-uniform via readlane(63).
__device__ __forceinline__ float wave_max64(float x) {
#define DSTEP(ctrl)                                                            \
    { int t_ = __builtin_amdgcn_update_dpp(__float_as_int(x), __float_as_int(x),\
                                           (ctrl), 0xF, 0xF, false);           \
      x = fmaxf(x, __int_as_float(t_)); }
    DSTEP(0x111) DSTEP(0x112) DSTEP(0x114) DSTEP(0x118) DSTEP(0x142) DSTEP(0x143)
#undef DSTEP
    return __int_as_float(__builtin_amdgcn_readlane(__float_as_int(x), 63));
}

// Async global->LDS, 4B/lane. Global address is PER-LANE (scattered gather ok);
// LDS destination is wave-uniform base + lane*4.
__device__ __forceinline__ void gload_lds4(const float* g, float* lds) {
    __builtin_amdgcn_global_load_lds(
        (const __attribute__((address_space(1))) void*)g,
        (__attribute__((address_space(3))) void*)lds, 4, 0, 0);
}

// One block (128 thr = 2 waves) per batch item.
// Wave 1 (producer): per chunk, 33 global_load_lds (32 label-row gathers + 1
//   blank gather) into a 4-slot LDS ring, issued 2 chunks ahead. Counted
//   s_waitcnt vmcnt(33) + raw s_barrier keep the next chunk's loads in
//   flight across the barrier. Junk lanes (l >= label_length) gather the
//   blank column instead of a random label column (same cache line as the
//   blank gather -> no extra HBM lines; their LDS values are zeroed by the
//   consumer anyway).
// Wave 0 (consumer): scaled-CTC in probability domain (r6-proven math,
//   INCLUDING the junk-lane emit zeroing: states beyond 2*label_length stay
//   exactly 0, so the renorm wave-max spans relevant states only -- without
//   this, junk states can push the readout states below the 2^-126 flush
//   floor, the r7 failure). Renorm every 4 steps by the wave-max exponent
//   with exact integer bookkeeping (eacc).
extern "C" __global__ __launch_bounds__(128) void ctc_fwd(
    const float* __restrict__ y_pred,
    const int* __restrict__ labels,
    const int* __restrict__ input_length,
    const int* __restrict__ label_length,
    float* __restrict__ out)
{
    const int b   = blockIdx.x;
    const int l   = threadIdx.x & 63;
    const int wid = threadIdx.x >> 6;

    __shared__ float lab_lds[NSLOT][CH][LLAB];
    __shared__ float blank_lds[NSLOT][LLAB];

    int len = input_length[b];
    len = len < 1 ? 1 : (len > TT ? TT : len);
    const int tmax = len - 1;
    const int nch  = (len - 1 + CH - 1) / CH;

    int llm = label_length[b];
    llm = llm < 1 ? 1 : (llm > LLAB ? LLAB : llm);

    const int  lab   = labels[b * LLAB + l];
    const bool ldlab = (l < llm);

    const float* __restrict__ yp = y_pred + (size_t)b * (TT * CC);
    const float* __restrict__ pl = yp + lab;       // this lane's label column
    const float* __restrict__ pb = yp + (CC - 1);  // blank column
    const float* __restrict__ psrc = ldlab ? pl : pb;  // junk lanes -> blank line

    float s0 = 0.f, s1 = 0.f, s2 = 0.f, skipf = 0.f;
    int   eacc = 0;

    // 33 async loads for chunk c into slot c%4. All 64 lanes active -> every
    // LDS byte of the slot gets written.
#define ISSUE_LDS(c)                                                         \
    if ((c) < nch) {                                                         \
        const int slot_ = (c) & (NSLOT - 1);                                 \
        const int t0 = 1 + (c) * CH;                                         \
        { int t = t0 + (l & (CH - 1)); t = t > tmax ? tmax : t;              \
          gload_lds4(pb + t * CC, &blank_lds[slot_][0]); }                   \
        _Pragma("unroll")                                                    \
        for (int j = 0; j < CH; ++j) {                                       \
            int t = t0 + j; t = t > tmax ? tmax : t;                         \
            gload_lds4(psrc + t * CC, &lab_lds[slot_][j][0]);                \
        }                                                                    \
    }

    if (wid == 1) {
        ISSUE_LDS(0);
        ISSUE_LDS(1);
    } else {
        const int labp = __shfl_up(lab, 1);
        skipf = (l >= 1 && lab != labp) ? 1.f : 0.f;
        if (l == 0) {                 // alpha0: states 0 and 1
            s0 = pb[0] + EPSF;
            s1 = pl[0] + EPSF;
        }
    }

    for (int k = 0; k < nch; ++k) {
        if (wid == 1) {
            // chunk k's 33 loads are oldest; chunk k+1's 33 stay in flight.
            if (k + 1 < nch) asm volatile("s_waitcnt vmcnt(33)" ::: "memory");
            else             asm volatile("s_waitcnt vmcnt(0)"  ::: "memory");
        }
        asm volatile("s_barrier" ::: "memory");   // raw: no implicit vmcnt(0) drain
        if (wid == 1) {
            ISSUE_LDS(k + 2);   // slot (k+2)%4: disjoint from k (read) and k+1 (ready)
        } else {
            const int slot = k & (NSLOT - 1);
            float e[CH], bb[CH];
#pragma unroll
            for (int j = 0; j < CH; ++j) {
                e[j]  = ldlab ? (lab_lds[slot][j][l] + EPSF) : 0.f;  // junk -> exact 0
                bb[j] = blank_lds[slot][j] + EPSF;
            }
#pragma unroll
            for (int j = 0; j < CH; ++j) {
                const int t = 1 + k * CH + j;
                float am1 = wave_shr1_zero(s1);
                float n0 = (s0 + am1) * bb[j];                    // state 2l
                float n1 = fmaf(am1, skipf, s1 + s0) * e[j];      // state 2l+1
                float n2 = (s2 + s1) * bb[j];                     // state 128
                const bool act = t < len;
                s0 = act ? n0 : s0;
                s1 = act ? n1 : s1;
                s2 = act ? n2 : s2;
                if ((j & 3) == 3) {   // renormalize every 4 steps (exact bookkeeping)
                    float m = wave_max64(fmaxf(fmaxf(s0, s1), s2));
                    int me = __float_as_int(m) >> 23;             // biased exponent
                    me = me < 26 ? 26 : me;                       // m==0 guard
                    float scale = __int_as_float((253 - me) << 23); // 2^(126-me)
                    s0 *= scale; s1 *= scale; s2 *= scale;
                    eacc += me - 126;
                }
            }
        }
    }

    if (wid == 0) {
        float v1 = __shfl(s1, llm - 1);                               // state 2ll-1
        float v2 = (llm < LLAB) ? __shfl(s0, llm) : __shfl(s2, 63);   // state 2ll
        float v  = fmaxf(v1 + v2, 1e-37f);
        if (l == 0) out[b] = -(__logf(v) + (float)eacc * LN2F);
    }
}

extern "C" void kernel_launch(void* const* d_in, const int* in_sizes, int n_in,
                              void* d_out, int out_size, void* d_ws, size_t ws_size,
                              hipStream_t stream) {
    (void)n_in; (void)out_size; (void)d_ws; (void)ws_size;
    const float* y_pred       = (const float*)d_in[0];
    const int*   labels       = (const int*)d_in[1];
    const int*   input_length = (const int*)d_in[2];
    const int*   label_length = (const int*)d_in[3];
    float* out = (float*)d_out;

    const int B = in_sizes[2];
    ctc_fwd<<<dim3(B), dim3(128), 0, stream>>>(y_pred, labels, input_length, label_length, out);
}